// Round 6
// baseline (144.397 us; speedup 1.0000x reference)
//
#include <hip/hip_runtime.h>
#include <math.h>

#define UDIM 512
#define DIN  256
#define BATCH 128
#define EPSV 1e-3f

#define GRP   64     // batches per group (A_g + Anew_g = 134 MB < L3)
#define NSLAB 8      // slabs per batch row-dim
#define RPB   64     // rows per slab
#define QR    16     // rows per thread (4 quarters x 16)

typedef float f4 __attribute__((ext_vector_type(4)));

// ---------------------------------------------------------------------------
// K1: pre = prev @ W_h + inputs @ C ; h = tanh(pre + bias)
// ---------------------------------------------------------------------------
__global__ __launch_bounds__(256) void k_pre(
    const float* __restrict__ inputs, const float* __restrict__ prev,
    const float* __restrict__ C, const float* __restrict__ Wh,
    const float* __restrict__ bias, float* __restrict__ pre, float* __restrict__ h)
{
    const int b = blockIdx.x >> 1;
    const int v = ((blockIdx.x & 1) << 8) + threadIdx.x;

    __shared__ float sprev[UDIM];
    __shared__ float sinp[DIN];
    for (int i = threadIdx.x; i < UDIM; i += 256) sprev[i] = prev[b * UDIM + i];
    sinp[threadIdx.x] = inputs[b * DIN + threadIdx.x];
    __syncthreads();

    float acc = 0.f;
#pragma unroll 8
    for (int u = 0; u < UDIM; ++u) acc = fmaf(sprev[u], Wh[u * UDIM + v], acc);
#pragma unroll 8
    for (int i = 0; i < DIN; ++i)  acc = fmaf(sinp[i], C[i * UDIM + v], acc);

    pre[b * UDIM + v] = acc;
    h[b * UDIM + v]   = tanhf(acc + bias[v]);
}

// ---------------------------------------------------------------------------
// K2 (per group): block (b, rs) streams 64 rows of A[b]:
//   Anew = 0.9*A + 0.5*h h^T (regular stores -> allocates L3, read by K3)
//   partial y1[v] = sum_{u in slab} h_u * Anew[u][v] -> ypart
// grid = GRP*8 = 512 blocks x 512 threads
// ---------------------------------------------------------------------------
__global__ __launch_bounds__(512) void k_mv0(
    const float* __restrict__ A, const float* __restrict__ h,
    float* __restrict__ Anew, float* __restrict__ ypart, const int bofs)
{
    const int bc  = blockIdx.x;
    const int b   = bofs + (bc >> 3);
    const int rs  = bc & 7;
    const int t   = threadIdx.x;
    const int vg  = t & 127;
    const int col = vg << 2;
    const int qtr = t >> 7;        // 0..3 -> 16 rows each

    __shared__ __align__(16) float sh[UDIM];
    __shared__ __align__(16) float spart[4][UDIM];

    sh[t] = h[(size_t)b * UDIM + t];
    __syncthreads();

    const f4 hv4 = *(const f4*)(sh + col);
    const int row0 = rs * RPB + qtr * QR;
    const float* __restrict__ Ab  = A    + ((size_t)b * UDIM + row0) * UDIM + col;
    float*       __restrict__ Anb = Anew + ((size_t)b * UDIM + row0) * UDIM + col;

    f4 acc = {0.f, 0.f, 0.f, 0.f};
#pragma unroll 8
    for (int k = 0; k < QR; ++k) {
        const f4 a4 = *(const f4*)(Ab + (size_t)k * UDIM);
        const float hu = sh[row0 + k];
        const float s = 0.5f * hu;
        f4 an;
        an.x = fmaf(s, hv4.x, 0.9f * a4.x);
        an.y = fmaf(s, hv4.y, 0.9f * a4.y);
        an.z = fmaf(s, hv4.z, 0.9f * a4.z);
        an.w = fmaf(s, hv4.w, 0.9f * a4.w);
        *(f4*)(Anb + (size_t)k * UDIM) = an;
        acc.x = fmaf(hu, an.x, acc.x);
        acc.y = fmaf(hu, an.y, acc.y);
        acc.z = fmaf(hu, an.z, acc.z);
        acc.w = fmaf(hu, an.w, acc.w);
    }
    *(f4*)(&spart[qtr][col]) = acc;
    __syncthreads();

    ypart[((size_t)b * NSLAB + rs) * UDIM + t] =
        spart[0][t] + spart[1][t] + spart[2][t] + spart[3][t];
}

// ---------------------------------------------------------------------------
// K3 (per group, steps 1,2): block (b, rs):
//   y = sum_s ypin; hs = tanh(pre+y); x = LN(hs)   (redundant per slab)
//   partial y'[v] = sum_{u in slab} x_u * Anew[u][v] -> ypout  (Anew L3-hot)
// ---------------------------------------------------------------------------
__global__ __launch_bounds__(512) void k_mv(
    const float* __restrict__ An, const float* __restrict__ pre,
    const float* __restrict__ ypin, const float* __restrict__ gamma,
    const float* __restrict__ beta, float* __restrict__ ypout, const int bofs)
{
    const int bc   = blockIdx.x;
    const int b    = bofs + (bc >> 3);
    const int rs   = bc & 7;
    const int t    = threadIdx.x;
    const int lane = t & 63;
    const int wave = t >> 6;       // 0..7
    const int vg   = t & 127;
    const int col  = vg << 2;
    const int qtr  = t >> 7;

    __shared__ __align__(16) float sx[UDIM];
    __shared__ __align__(16) float spart[4][UDIM];
    __shared__ float sred[16];
    __shared__ float sbc[2];

    // combine partials -> hs -> LN stats
    float hs;
    {
        float y = 0.f;
#pragma unroll
        for (int s = 0; s < NSLAB; ++s)
            y += ypin[((size_t)b * NSLAB + s) * UDIM + t];
        hs = tanhf(pre[(size_t)b * UDIM + t] + y);
        float s1 = hs, s2 = hs * hs;
#pragma unroll
        for (int off = 32; off; off >>= 1) {
            s1 += __shfl_xor(s1, off, 64);
            s2 += __shfl_xor(s2, off, 64);
        }
        if (lane == 0) { sred[wave] = s1; sred[8 + wave] = s2; }
    }
    __syncthreads();
    if (t == 0) {
        float m = 0.f, q = 0.f;
#pragma unroll
        for (int i = 0; i < 8; ++i) { m += sred[i]; q += sred[8 + i]; }
        m *= (1.f / UDIM);
        q = q * (1.f / UDIM) - m * m;
        sbc[0] = m;
        sbc[1] = rsqrtf(q + EPSV);
    }
    __syncthreads();
    sx[t] = (hs - sbc[0]) * sbc[1] * gamma[t] + beta[t];
    __syncthreads();

    const int row0 = rs * RPB + qtr * QR;
    const float* __restrict__ Ab = An + ((size_t)b * UDIM + row0) * UDIM + col;

    f4 acc = {0.f, 0.f, 0.f, 0.f};
#pragma unroll 8
    for (int k = 0; k < QR; ++k) {
        const f4 a4 = *(const f4*)(Ab + (size_t)k * UDIM);
        const float xu = sx[row0 + k];
        acc.x = fmaf(xu, a4.x, acc.x);
        acc.y = fmaf(xu, a4.y, acc.y);
        acc.z = fmaf(xu, a4.z, acc.z);
        acc.w = fmaf(xu, a4.w, acc.w);
    }
    *(f4*)(&spart[qtr][col]) = acc;
    __syncthreads();

    ypout[((size_t)b * NSLAB + rs) * UDIM + t] =
        spart[0][t] + spart[1][t] + spart[2][t] + spart[3][t];
}

// ---------------------------------------------------------------------------
// K4: out = LN(tanh(pre + sum ypart))  (all 128 batches)
// ---------------------------------------------------------------------------
__global__ __launch_bounds__(512) void k_fin(
    const float* __restrict__ pre, const float* __restrict__ ypin,
    const float* __restrict__ gamma, const float* __restrict__ beta,
    float* __restrict__ out)
{
    const int b    = blockIdx.x;
    const int t    = threadIdx.x;
    const int lane = t & 63;
    const int wave = t >> 6;   // 0..7

    __shared__ float sred[16];
    __shared__ float sbc[2];

    float y = 0.f;
#pragma unroll
    for (int s = 0; s < NSLAB; ++s) y += ypin[((size_t)b * NSLAB + s) * UDIM + t];
    const float hs = tanhf(pre[(size_t)b * UDIM + t] + y);

    float s1 = hs, s2 = hs * hs;
#pragma unroll
    for (int off = 32; off; off >>= 1) {
        s1 += __shfl_xor(s1, off, 64);
        s2 += __shfl_xor(s2, off, 64);
    }
    if (lane == 0) { sred[wave] = s1; sred[8 + wave] = s2; }
    __syncthreads();
    if (t == 0) {
        float m = 0.f, q = 0.f;
#pragma unroll
        for (int i = 0; i < 8; ++i) { m += sred[i]; q += sred[8 + i]; }
        m *= (1.f / UDIM);
        q = q * (1.f / UDIM) - m * m;
        sbc[0] = m;
        sbc[1] = rsqrtf(q + EPSV);
    }
    __syncthreads();
    out[(size_t)b * UDIM + t] = (hs - sbc[0]) * sbc[1] * gamma[t] + beta[t];
}

// ---------------------------------------------------------------------------
extern "C" void kernel_launch(void* const* d_in, const int* in_sizes, int n_in,
                              void* d_out, int out_size, void* d_ws, size_t ws_size,
                              hipStream_t stream) {
    const float* inputs = (const float*)d_in[0];
    const float* prev   = (const float*)d_in[1];
    const float* A      = (const float*)d_in[2];
    const float* C      = (const float*)d_in[3];
    const float* Wh     = (const float*)d_in[4];
    const float* bias   = (const float*)d_in[5];
    const float* gamma  = (const float*)d_in[6];
    const float* beta   = (const float*)d_in[7];

    float* out  = (float*)d_out;                  // (128,512)
    float* Anew = out + (size_t)BATCH * UDIM;     // (128,512,512)

    float* pre  = (float*)d_ws;                         // 128*512
    float* h    = pre  + (size_t)BATCH * UDIM;          // 128*512
    float* ypA  = h    + (size_t)BATCH * UDIM;          // 128*8*512
    float* ypB  = ypA  + (size_t)BATCH * NSLAB * UDIM;  // 128*8*512

    k_pre<<<BATCH * 2, 256, 0, stream>>>(inputs, prev, C, Wh, bias, pre, h);

    // group 0 (batches 0..63): pass0 writes Anew_g -> L3; passes 1,2 read it hot
    k_mv0<<<GRP * NSLAB, 512, 0, stream>>>(A, h, Anew, ypA, 0);
    k_mv <<<GRP * NSLAB, 512, 0, stream>>>(Anew, pre, ypA, gamma, beta, ypB, 0);
    k_mv <<<GRP * NSLAB, 512, 0, stream>>>(Anew, pre, ypB, gamma, beta, ypA, 0);

    // group 1 (batches 64..127)
    k_mv0<<<GRP * NSLAB, 512, 0, stream>>>(A, h, Anew, ypA, GRP);
    k_mv <<<GRP * NSLAB, 512, 0, stream>>>(Anew, pre, ypA, gamma, beta, ypB, GRP);
    k_mv <<<GRP * NSLAB, 512, 0, stream>>>(Anew, pre, ypB, gamma, beta, ypA, GRP);

    k_fin<<<BATCH, 512, 0, stream>>>(pre, ypA, gamma, beta, out);
}